// Round 1
// baseline (72.375 us; speedup 1.0000x reference)
//
#include <hip/hip_runtime.h>
#include <math.h>

#define HN 1024
#define VN 50257
#define SN 8192

// ws layout (float offsets)
#define WS_PARTIAL 0          // 256*1024 floats: per-rowchunk column partial sums
#define WS_AA      262144     // 1024: attn_applied (column mean)
#define WS_X       263168     // 1024: relu(combined)
#define WS_G       264192     // 6144: gi (3072) then gh (3072)
#define WS_HNEW    270336     // 1024: h_new
#define WS_LOGITS  271360     // 50257
#define WS_EXPD    321618     // 1024 doubles (2048 float slots), byte offset % 8 == 0
#define WS_LOGZ    323666     // 1 float

__device__ __forceinline__ float wred(float v) {
#pragma unroll
  for (int m = 32; m; m >>= 1) v += __shfl_xor(v, m);
  return v;
}

// K1a: per-rowchunk column sums of encoder_outputs + write uniform attn_weights out
__global__ void k1a_colsum(const float* __restrict__ enc, float* __restrict__ ws,
                           float* __restrict__ out_attn) {
  const int rc = blockIdx.x;          // 0..255, 32 rows each
  const int t = threadIdx.x;          // 256 threads, 4 cols each (float4)
  const float4* e4 = (const float4*)enc;
  float4 acc = make_float4(0.f, 0.f, 0.f, 0.f);
  const int rbase = rc * 32;
#pragma unroll 8
  for (int r = 0; r < 32; ++r) {
    float4 v = e4[(size_t)(rbase + r) * 256 + t];
    acc.x += v.x; acc.y += v.y; acc.z += v.z; acc.w += v.w;
  }
  ((float4*)(ws + WS_PARTIAL))[rc * 256 + t] = acc;
  if (t < 32) out_attn[rc * 32 + t] = 1.f / 8192.f;  // softmax(const) == uniform, exact
}

// K1b: reduce 256 rowchunk partials -> attn_applied (column mean)
__global__ void k1b_reduce(float* __restrict__ ws) {
  const int c = blockIdx.x * 256 + threadIdx.x;  // 0..1023
  const float* p = ws + WS_PARTIAL;
  float s = 0.f;
#pragma unroll 8
  for (int rc = 0; rc < 256; ++rc) s += p[rc * 1024 + c];
  ws[WS_AA + c] = s * (1.f / 8192.f);
}

// K2: x = relu(concat(emb, attn_applied) @ comb_w.T + comb_b) ; one wave per row
__global__ void k2_combined(const int* __restrict__ token,
                            const float* __restrict__ embedding,
                            const float* __restrict__ comb_w,
                            const float* __restrict__ comb_b,
                            float* __restrict__ ws) {
  const int w = threadIdx.x >> 6, l = threadIdx.x & 63;
  const int i = blockIdx.x * 4 + w;  // 0..1023
  const int tok = token[0];
  const float4* emb4 = (const float4*)embedding + (size_t)tok * 256;
  const float4* aa4 = (const float4*)(ws + WS_AA);
  const float4* cw4 = (const float4*)comb_w + (size_t)i * 512;
  float acc = 0.f;
#pragma unroll
  for (int k = 0; k < 8; ++k) {
    float4 wv = cw4[k * 64 + l];
    float4 xv = (k < 4) ? emb4[k * 64 + l] : aa4[(k - 4) * 64 + l];
    acc += wv.x * xv.x + wv.y * xv.y + wv.z * xv.z + wv.w * xv.w;
  }
  acc = wred(acc);
  if (l == 0) {
    float c = acc + comb_b[i];
    ws[WS_X + i] = c > 0.f ? c : 0.f;
  }
}

// K3a: g[0:3072] = w_ih @ x ; g[3072:6144] = w_hh @ h0 ; one wave per row
__global__ void k3a_gates(const float* __restrict__ w_ih,
                          const float* __restrict__ w_hh,
                          const float* __restrict__ hidden,
                          float* __restrict__ ws) {
  const int w = threadIdx.x >> 6, l = threadIdx.x & 63;
  const int r = blockIdx.x * 4 + w;  // 0..6143
  const bool ih = (r < 3072);
  const float4* m4 = ih ? ((const float4*)w_ih + (size_t)r * 256)
                        : ((const float4*)w_hh + (size_t)(r - 3072) * 256);
  const float4* v4 = ih ? (const float4*)(ws + WS_X) : (const float4*)hidden;
  float acc = 0.f;
#pragma unroll
  for (int k = 0; k < 4; ++k) {
    float4 a = m4[k * 64 + l];
    float4 b = v4[k * 64 + l];
    acc += a.x * b.x + a.y * b.y + a.z * b.z + a.w * b.w;
  }
  acc = wred(acc);
  if (l == 0) ws[WS_G + r] = acc;
}

// K3b: GRU gate math -> h_new (ws + d_out)
__global__ void k3b_hnew(const float* __restrict__ b_ih, const float* __restrict__ b_hh,
                         const float* __restrict__ hidden, float* __restrict__ ws,
                         float* __restrict__ d_out) {
  const int i = blockIdx.x * 256 + threadIdx.x;  // 0..1023
  const float* g = ws + WS_G;
  float ir = g[i] + b_ih[i];
  float iz = g[i + 1024] + b_ih[i + 1024];
  float inn = g[i + 2048] + b_ih[i + 2048];
  float hr = g[3072 + i] + b_hh[i];
  float hz = g[3072 + i + 1024] + b_hh[i + 1024];
  float hn = g[3072 + i + 2048] + b_hh[i + 2048];
  float rg = 1.f / (1.f + expf(-(ir + hr)));
  float zg = 1.f / (1.f + expf(-(iz + hz)));
  float ng = tanhf(inn + rg * hn);
  float h0i = hidden[i];
  float h = (1.f - zg) * ng + zg * h0i;
  ws[WS_HNEW + i] = h;
  d_out[VN + i] = h;  // h_new output region
}

// K4: logits[v] = out_w[v] . h_new + out_b[v] ; per-block partial sum of exp(logit)
__global__ void k4_logits(const float* __restrict__ out_w, const float* __restrict__ out_b,
                          float* __restrict__ ws) {
  const int w = threadIdx.x >> 6, l = threadIdx.x & 63;
  const int gw = blockIdx.x * 4 + w;  // 0..4095 global wave id
  const float4* h4p = (const float4*)(ws + WS_HNEW);
  float4 h4[4];
#pragma unroll
  for (int k = 0; k < 4; ++k) h4[k] = h4p[k * 64 + l];
  const float4* ow4 = (const float4*)out_w;
  float* logits = ws + WS_LOGITS;
  double eacc = 0.0;
  for (int v = gw; v < VN; v += 4096) {
    float acc = 0.f;
#pragma unroll
    for (int k = 0; k < 4; ++k) {
      float4 a = ow4[(size_t)v * 256 + k * 64 + l];
      acc += a.x * h4[k].x + a.y * h4[k].y + a.z * h4[k].z + a.w * h4[k].w;
    }
    acc = wred(acc);
    if (l == 0) {
      float lg = acc + out_b[v];
      logits[v] = lg;
      eacc += (double)expf(lg);  // |logit| ~ O(4): no overflow without max-subtract
    }
  }
  __shared__ double se[4];
  if (l == 0) se[w] = eacc;
  __syncthreads();
  if (threadIdx.x == 0) {
    double* ed = (double*)(ws + WS_EXPD);
    ed[blockIdx.x] = se[0] + se[1] + se[2] + se[3];
  }
}

// K5: reduce 1024 partial exp-sums (deterministic ordered tree) -> logZ
__global__ void k5_logz(float* __restrict__ ws) {
  __shared__ double sd[256];
  const int t = threadIdx.x;
  const double* ed = (const double*)(ws + WS_EXPD);
  double a = 0.0;
#pragma unroll
  for (int i = 0; i < 4; ++i) a += ed[t + i * 256];
  sd[t] = a;
  __syncthreads();
  for (int s = 128; s > 0; s >>= 1) {
    if (t < s) sd[t] += sd[t + s];
    __syncthreads();
  }
  if (t == 0) ws[WS_LOGZ] = (float)log(sd[0]);
}

// K6: out[v] = logits[v] - logZ
__global__ void k6_final(const float* __restrict__ ws, float* __restrict__ d_out) {
  const int v = blockIdx.x * 256 + threadIdx.x;
  if (v < VN) d_out[v] = ws[WS_LOGITS + v] - ws[WS_LOGZ];
}

extern "C" void kernel_launch(void* const* d_in, const int* in_sizes, int n_in,
                              void* d_out, int out_size, void* d_ws, size_t ws_size,
                              hipStream_t stream) {
  const int* token = (const int*)d_in[0];
  const float* hidden = (const float*)d_in[1];
  const float* enc = (const float*)d_in[2];
  const float* embedding = (const float*)d_in[3];
  // d_in[4] attn_w, d_in[5] attn_b: softmax(broadcast(scalar)) is uniform -> unused
  const float* comb_w = (const float*)d_in[6];
  const float* comb_b = (const float*)d_in[7];
  const float* w_ih = (const float*)d_in[8];
  const float* w_hh = (const float*)d_in[9];
  const float* b_ih = (const float*)d_in[10];
  const float* b_hh = (const float*)d_in[11];
  const float* out_w = (const float*)d_in[12];
  const float* out_b = (const float*)d_in[13];
  float* out = (float*)d_out;
  float* ws = (float*)d_ws;

  float* out_attn = out + VN + HN;  // attn_weights region [S]

  k1a_colsum<<<256, 256, 0, stream>>>(enc, ws, out_attn);
  k1b_reduce<<<4, 256, 0, stream>>>(ws);
  k2_combined<<<256, 256, 0, stream>>>(token, embedding, comb_w, comb_b, ws);
  k3a_gates<<<1536, 256, 0, stream>>>(w_ih, w_hh, hidden, ws);
  k3b_hnew<<<4, 256, 0, stream>>>(b_ih, b_hh, hidden, ws, out);
  k4_logits<<<1024, 256, 0, stream>>>(out_w, out_b, ws);
  k5_logz<<<1, 256, 0, stream>>>(ws);
  k6_final<<<197, 256, 0, stream>>>(ws, out);
}